// Round 6
// baseline (1184.955 us; speedup 1.0000x reference)
//
#include <hip/hip_runtime.h>

// EdgeSageLayer on MI355X — round 6.
// agg[n] = (sum_{e:dst=n} concat(x[src_e], ea_e)) @ msg_w / deg + msg_b*(deg>0)
// R5 postmortem: (a) 4-node/wave aggregate cut wave count in half -> latency
// bound got worse (occupancy 67->39%); (b) ~170+ us/call is spread across 9
// dispatches that never show in top-5. R6: ONE persistent kernel (1008 blocks,
// co-resident by construction) with device-scope grid barriers between
// phases; aggregate back to 2 nodes/wave with (edge,src) pairs.

constexpr int N_NODES  = 50000;
constexpr int N_EDGES  = 800000;
constexpr int IN_DIM   = 64;
constexpr int EDGE_DIM = 32;
constexpr int OUT_DIM  = 64;
constexpr int NBLK     = 1008;   // <= 4 blocks/CU * 252 CUs: co-resident even with harvested CUs
constexpr int NTHR     = 256;

// ---------------------------------------------------------------------------
// Grid barrier: device-scope atomics + fences. All NBLK blocks co-resident
// (launch_bounds caps VGPR at 128 -> 16 waves/CU -> 4 blocks/CU; 0 LDS).
// ---------------------------------------------------------------------------
__device__ __forceinline__ void gbar(int* bcount, int* bgen) {
    __syncthreads();
    if (threadIdx.x == 0) {
        __threadfence();  // release: flush this CU/XCD's writes
        const int g = __hip_atomic_load(bgen, __ATOMIC_ACQUIRE, __HIP_MEMORY_SCOPE_AGENT);
        const int a = __hip_atomic_fetch_add(bcount, 1, __ATOMIC_ACQ_REL, __HIP_MEMORY_SCOPE_AGENT);
        if (a == NBLK - 1) {
            __hip_atomic_store(bcount, 0, __ATOMIC_RELAXED, __HIP_MEMORY_SCOPE_AGENT);
            __hip_atomic_fetch_add(bgen, 1, __ATOMIC_RELEASE, __HIP_MEMORY_SCOPE_AGENT);
        } else {
            while (__hip_atomic_load(bgen, __ATOMIC_ACQUIRE, __HIP_MEMORY_SCOPE_AGENT) == g)
                __builtin_amdgcn_s_sleep(2);
        }
        __threadfence();  // acquire: invalidate stale cached lines
    }
    __syncthreads();
}

// ---------------------------------------------------------------------------
// The whole layer in one kernel. Phases separated by grid barriers:
//  P1 count -> P2 alloc -> P3 place pairs -> P4 gather-reduce -> P5 msg+self.
// ---------------------------------------------------------------------------
__global__ __launch_bounds__(NTHR, 4) void fused_k(
    const float* __restrict__ x, const int* __restrict__ ei,
    const float* __restrict__ ea,
    const float* __restrict__ msg_w, const float* __restrict__ msg_b,
    const float* __restrict__ self_w, const float* __restrict__ self_b,
    float* out,            // also the sum_x accumulator
    int* cnt, int* cursor, int* bar, int* cur, int2* pairs,
    float* sum_ea)
{
    const int tid    = blockIdx.x * NTHR + threadIdx.x;
    const int nthr   = NBLK * NTHR;
    const int lane   = threadIdx.x & 63;
    const int wave   = tid >> 6;
    const int nwaves = nthr >> 6;

    // ---- P1: histogram of dst (N_EDGES % 4 == 0) ----
    for (int t = tid; t < N_EDGES / 4; t += nthr) {
        const int4 d4 = ((const int4*)(ei + N_EDGES))[t];
        atomicAdd(&cnt[d4.x], 1); atomicAdd(&cnt[d4.y], 1);
        atomicAdd(&cnt[d4.z], 1); atomicAdd(&cnt[d4.w], 1);
    }
    gbar(bar, bar + 1);

    // ---- P2: allocate CSR ranges (wave scan + one cursor atomic/chunk) ----
    for (int base = wave * 64; base < N_NODES; base += nwaves * 64) {
        const int n = base + lane;
        const int c = (n < N_NODES) ? cnt[n] : 0;
        int v = c;
#pragma unroll
        for (int d = 1; d < 64; d <<= 1) {
            int t = __shfl_up(v, d);
            if (lane >= d) v += t;
        }
        const int total = __shfl(v, 63);
        int b = 0;
        if (lane == 0) b = atomicAdd(cursor, total);
        b = __shfl(b, 0);
        if (n < N_NODES) cur[n] = b + v - c;   // exclusive start
    }
    gbar(bar, bar + 1);

    // ---- P3: place (edge, src) pairs ----
    for (int t = tid; t < N_EDGES / 4; t += nthr) {
        const int4 d4 = ((const int4*)(ei + N_EDGES))[t];
        const int4 s4 = ((const int4*)ei)[t];
        pairs[atomicAdd(&cur[d4.x], 1)] = make_int2(4 * t + 0, s4.x);
        pairs[atomicAdd(&cur[d4.y], 1)] = make_int2(4 * t + 1, s4.y);
        pairs[atomicAdd(&cur[d4.z], 1)] = make_int2(4 * t + 2, s4.z);
        pairs[atomicAdd(&cur[d4.w], 1)] = make_int2(4 * t + 3, s4.w);
    }
    gbar(bar, bar + 1);

    // ---- P4: gather-reduce, 2 nodes/wave interleaved ----
    {
        const int grpx = lane >> 4, colx = lane & 15;  // x: 4 edges/step
        const int grpe = lane >> 3, cole = lane & 7;   // ea: 8 edges/step

        for (int n0 = wave * 2; n0 < N_NODES; n0 += nwaves * 2) {
            const int  nA   = __builtin_amdgcn_readfirstlane(n0);
            const bool hasB = (n0 + 1 < N_NODES);
            const int  nB   = nA + 1;

            const int cA = __builtin_amdgcn_readfirstlane(cnt[nA]);
            const int sA = __builtin_amdgcn_readfirstlane(cur[nA]) - cA;
            const int cB = hasB ? __builtin_amdgcn_readfirstlane(cnt[nB]) : 0;
            const int sB = hasB ? __builtin_amdgcn_readfirstlane(cur[nB]) - cB : 0;

            float4 axA = {0,0,0,0}, aeA = {0,0,0,0};
            float4 axB = {0,0,0,0}, aeB = {0,0,0,0};

            for (int base = 0; base < max(cA, cB); base += 64) {
                const int mA = min(64, cA - base) > 0 ? min(64, cA - base) : 0;
                const int mB = min(64, cB - base) > 0 ? min(64, cB - base) : 0;

                int eA = 0, srcA = 0, eB = 0, srcB = 0;
                if (lane < mA) { const int2 p = pairs[sA + base + lane]; eA = p.x; srcA = p.y; }
                if (lane < mB) { const int2 p = pairs[sB + base + lane]; eB = p.x; srcB = p.y; }

                const int mMax = max(mA, mB);
                for (int j = 0; j < mMax; j += 4) {
                    const int jj  = j + grpx;
                    const int sjA = __shfl(srcA, jj);
                    const int sjB = __shfl(srcB, jj);
                    if (jj < mA) {
                        const float4 v = ((const float4*)(x + (size_t)sjA * IN_DIM))[colx];
                        axA.x += v.x; axA.y += v.y; axA.z += v.z; axA.w += v.w;
                    }
                    if (jj < mB) {
                        const float4 v = ((const float4*)(x + (size_t)sjB * IN_DIM))[colx];
                        axB.x += v.x; axB.y += v.y; axB.z += v.z; axB.w += v.w;
                    }
                }
                for (int j = 0; j < mMax; j += 8) {
                    const int jj  = j + grpe;
                    const int ejA = __shfl(eA, jj);
                    const int ejB = __shfl(eB, jj);
                    if (jj < mA) {
                        const float4 v = ((const float4*)(ea + (size_t)ejA * EDGE_DIM))[cole];
                        aeA.x += v.x; aeA.y += v.y; aeA.z += v.z; aeA.w += v.w;
                    }
                    if (jj < mB) {
                        const float4 v = ((const float4*)(ea + (size_t)ejB * EDGE_DIM))[cole];
                        aeB.x += v.x; aeB.y += v.y; aeB.z += v.z; aeB.w += v.w;
                    }
                }
            }

#pragma unroll
            for (int mask = 16; mask < 64; mask <<= 1) {
                axA.x += __shfl_xor(axA.x, mask); axA.y += __shfl_xor(axA.y, mask);
                axA.z += __shfl_xor(axA.z, mask); axA.w += __shfl_xor(axA.w, mask);
                axB.x += __shfl_xor(axB.x, mask); axB.y += __shfl_xor(axB.y, mask);
                axB.z += __shfl_xor(axB.z, mask); axB.w += __shfl_xor(axB.w, mask);
            }
#pragma unroll
            for (int mask = 8; mask < 64; mask <<= 1) {
                aeA.x += __shfl_xor(aeA.x, mask); aeA.y += __shfl_xor(aeA.y, mask);
                aeA.z += __shfl_xor(aeA.z, mask); aeA.w += __shfl_xor(aeA.w, mask);
                aeB.x += __shfl_xor(aeB.x, mask); aeB.y += __shfl_xor(aeB.y, mask);
                aeB.z += __shfl_xor(aeB.z, mask); aeB.w += __shfl_xor(aeB.w, mask);
            }

            if (lane < 16) ((float4*)(out + (size_t)nA * IN_DIM))[lane] = axA;
            if (lane < 8)  ((float4*)(sum_ea + (size_t)nA * EDGE_DIM))[lane] = aeA;
            if (hasB) {
                if (lane < 16) ((float4*)(out + (size_t)nB * IN_DIM))[lane] = axB;
                if (lane < 8)  ((float4*)(sum_ea + (size_t)nB * EDGE_DIM))[lane] = aeB;
            }
        }
    }
    gbar(bar, bar + 1);

    // ---- P5a: msg projection (96 weights/lane). Wave w owns nodes
    //       w, w+W, ...; overwrites out rows it alone reads/writes. ----
    const int c = lane;  // output column
    {
        float wm[96];
#pragma unroll
        for (int k = 0; k < 96; ++k) wm[k] = msg_w[k * OUT_DIM + c];
        const float mb = msg_b[c];

        for (int n0 = wave; n0 < N_NODES; n0 += nwaves) {
            const int n = __builtin_amdgcn_readfirstlane(n0);
            const float4* r1 = (const float4*)(out    + (size_t)n * IN_DIM);
            const float4* r2 = (const float4*)(sum_ea + (size_t)n * EDGE_DIM);
            const int d = cnt[n];

            float a0 = 0.f, a1 = 0.f, a2 = 0.f, a3 = 0.f;
#pragma unroll
            for (int q = 0; q < 16; ++q) {
                const float4 v = r1[q];
                a0 = fmaf(v.x, wm[4 * q + 0], a0);
                a1 = fmaf(v.y, wm[4 * q + 1], a1);
                a2 = fmaf(v.z, wm[4 * q + 2], a2);
                a3 = fmaf(v.w, wm[4 * q + 3], a3);
            }
#pragma unroll
            for (int q = 0; q < 8; ++q) {
                const float4 v = r2[q];
                a0 = fmaf(v.x, wm[64 + 4 * q + 0], a0);
                a1 = fmaf(v.y, wm[64 + 4 * q + 1], a1);
                a2 = fmaf(v.z, wm[64 + 4 * q + 2], a2);
                a3 = fmaf(v.w, wm[64 + 4 * q + 3], a3);
            }
            const float inv  = 1.0f / (float)max(d, 1);
            const float bsel = (d > 0) ? 1.0f : 0.0f;
            out[(size_t)n * OUT_DIM + c] = ((a0 + a1) + (a2 + a3)) * inv + mb * bsel;
        }
    }
    __syncthreads();  // fence: keep wsf loads from hoisting into P5a (reg pressure)

    // ---- P5b: self projection (64 weights/lane), same wave->node map ----
    {
        float wsf[64];
#pragma unroll
        for (int k = 0; k < 64; ++k) wsf[k] = self_w[k * OUT_DIM + c];
        const float sb = self_b[c];

        for (int n0 = wave; n0 < N_NODES; n0 += nwaves) {
            const int n = __builtin_amdgcn_readfirstlane(n0);
            const float4* r3 = (const float4*)(x + (size_t)n * IN_DIM);

            float a0 = 0.f, a1 = 0.f, a2 = 0.f, a3 = 0.f;
#pragma unroll
            for (int q = 0; q < 16; ++q) {
                const float4 v = r3[q];
                a0 = fmaf(v.x, wsf[4 * q + 0], a0);
                a1 = fmaf(v.y, wsf[4 * q + 1], a1);
                a2 = fmaf(v.z, wsf[4 * q + 2], a2);
                a3 = fmaf(v.w, wsf[4 * q + 3], a3);
            }
            out[(size_t)n * OUT_DIM + c] += (a0 + a1) + (a2 + a3) + sb;
        }
    }
}

// ---------------------------------------------------------------------------
// Fallback kernels (ws too small for CSR): R1-style atomic scatter + finalize.
// ---------------------------------------------------------------------------
__global__ __launch_bounds__(768) void scatter_fb_k(
    const float* __restrict__ x, const int* __restrict__ ei,
    const float* __restrict__ ea, float* sum_x, float* sum_ea, int* deg)
{
    const int t  = threadIdx.x;
    const int el = t / 96;
    const int k  = t - el * 96;
    const int e  = blockIdx.x * 8 + el;
    if (e >= N_EDGES) return;
    const int dst = ei[N_EDGES + e];
    if (k < IN_DIM) {
        const int src = ei[e];
        atomicAdd(&sum_x[dst * IN_DIM + k], x[src * IN_DIM + k]);
        if (k == 0) atomicAdd(&deg[dst], 1);
    } else {
        const int kk = k - IN_DIM;
        atomicAdd(&sum_ea[dst * EDGE_DIM + kk], ea[e * EDGE_DIM + kk]);
    }
}

__global__ __launch_bounds__(256) void msg_fb_k(
    const float* sum_x_in, const float* __restrict__ sum_ea,
    const int* __restrict__ cnt,
    const float* __restrict__ msg_w, const float* __restrict__ msg_b,
    float* out)
{
    const int c = threadIdx.x & 63;
    float wm[96];
#pragma unroll
    for (int k = 0; k < 96; ++k) wm[k] = msg_w[k * OUT_DIM + c];
    const float mb = msg_b[c];
    const int wave   = (blockIdx.x * blockDim.x + threadIdx.x) >> 6;
    const int nwaves = (gridDim.x * blockDim.x) >> 6;
    for (int n0 = wave; n0 < N_NODES; n0 += nwaves) {
        const int n = __builtin_amdgcn_readfirstlane(n0);
        const float4* r1 = (const float4*)(sum_x_in + (size_t)n * IN_DIM);
        const float4* r2 = (const float4*)(sum_ea   + (size_t)n * EDGE_DIM);
        const int d = cnt[n];
        float a0 = 0.f, a1 = 0.f, a2 = 0.f, a3 = 0.f;
#pragma unroll
        for (int q = 0; q < 16; ++q) {
            const float4 v = r1[q];
            a0 = fmaf(v.x, wm[4 * q + 0], a0); a1 = fmaf(v.y, wm[4 * q + 1], a1);
            a2 = fmaf(v.z, wm[4 * q + 2], a2); a3 = fmaf(v.w, wm[4 * q + 3], a3);
        }
#pragma unroll
        for (int q = 0; q < 8; ++q) {
            const float4 v = r2[q];
            a0 = fmaf(v.x, wm[64 + 4 * q + 0], a0); a1 = fmaf(v.y, wm[64 + 4 * q + 1], a1);
            a2 = fmaf(v.z, wm[64 + 4 * q + 2], a2); a3 = fmaf(v.w, wm[64 + 4 * q + 3], a3);
        }
        const float inv  = 1.0f / (float)max(d, 1);
        const float bsel = (d > 0) ? 1.0f : 0.0f;
        out[(size_t)n * OUT_DIM + c] = ((a0 + a1) + (a2 + a3)) * inv + mb * bsel;
    }
}

__global__ __launch_bounds__(256) void self_fb_k(
    const float* __restrict__ x,
    const float* __restrict__ self_w, const float* __restrict__ self_b,
    float* out)
{
    const int c = threadIdx.x & 63;
    float wsf[64];
#pragma unroll
    for (int k = 0; k < 64; ++k) wsf[k] = self_w[k * OUT_DIM + c];
    const float sb = self_b[c];
    const int wave   = (blockIdx.x * blockDim.x + threadIdx.x) >> 6;
    const int nwaves = (gridDim.x * blockDim.x) >> 6;
    for (int n0 = wave; n0 < N_NODES; n0 += nwaves) {
        const int n = __builtin_amdgcn_readfirstlane(n0);
        const float4* r3 = (const float4*)(x + (size_t)n * IN_DIM);
        float a0 = 0.f, a1 = 0.f, a2 = 0.f, a3 = 0.f;
#pragma unroll
        for (int q = 0; q < 16; ++q) {
            const float4 v = r3[q];
            a0 = fmaf(v.x, wsf[4 * q + 0], a0); a1 = fmaf(v.y, wsf[4 * q + 1], a1);
            a2 = fmaf(v.z, wsf[4 * q + 2], a2); a3 = fmaf(v.w, wsf[4 * q + 3], a3);
        }
        out[(size_t)n * OUT_DIM + c] += (a0 + a1) + (a2 + a3) + sb;
    }
}

// ---------------------------------------------------------------------------
extern "C" void kernel_launch(void* const* d_in, const int* in_sizes, int n_in,
                              void* d_out, int out_size, void* d_ws, size_t ws_size,
                              hipStream_t stream) {
    const float* x      = (const float*)d_in[0];
    const int*   ei     = (const int*)d_in[1];   // [2][E]
    const float* ea     = (const float*)d_in[2];
    const float* msg_w  = (const float*)d_in[3];
    const float* msg_b  = (const float*)d_in[4];
    const float* self_w = (const float*)d_in[5];
    const float* self_b = (const float*)d_in[6];

    float* out = (float*)d_out;  // doubles as sum_x accumulator

    // ws layout (ints unless noted):
    //   cnt[50000] | cursor[1] | bar[2] | pad to 16 | cur[50000]
    //   | pairs[800000 int2] | sum_ea[1.6M floats]
    int*   cnt    = (int*)d_ws;
    int*   cursor = cnt + N_NODES;
    int*   bar    = cursor + 1;
    int*   cur    = cnt + N_NODES + 16;
    int2*  pairs  = (int2*)(cur + N_NODES);
    float* sum_ea = (float*)(pairs + N_EDGES);
    const size_t need =
        ((size_t)N_NODES + 16 + N_NODES + 2 * (size_t)N_EDGES +
         (size_t)N_NODES * EDGE_DIM) * sizeof(int);

    if (ws_size >= need) {
        // zero cnt + cursor + barrier state in one small memset
        hipMemsetAsync(cnt, 0, (N_NODES + 16) * sizeof(int), stream);
        fused_k<<<NBLK, NTHR, 0, stream>>>(
            x, ei, ea, msg_w, msg_b, self_w, self_b,
            out, cnt, cursor, bar, cur, pairs, sum_ea);
    } else {
        // Fallback: atomic scatter (needs only sum_ea + deg ~ 6.6 MB)
        float* fb_sum_ea = (float*)d_ws;
        int*   deg       = (int*)(fb_sum_ea + (size_t)N_NODES * EDGE_DIM);
        hipMemsetAsync(d_out, 0, (size_t)N_NODES * OUT_DIM * sizeof(float), stream);
        hipMemsetAsync(d_ws, 0, (size_t)N_NODES * (EDGE_DIM + 1) * sizeof(float), stream);
        scatter_fb_k<<<(N_EDGES + 7) / 8, 768, 0, stream>>>(
            x, ei, ea, out, fb_sum_ea, deg);
        msg_fb_k<<<1024, 256, 0, stream>>>(out, fb_sum_ea, deg, msg_w, msg_b, out);
        self_fb_k<<<1024, 256, 0, stream>>>(x, self_w, self_b, out);
    }
}

// Round 7
// 299.213 us; speedup vs baseline: 3.9602x; 3.9602x over previous
//
#include <hip/hip_runtime.h>

// EdgeSageLayer on MI355X — round 7.
// agg[n] = (sum_{e:dst=n} concat(x[src_e], ea_e)) @ msg_w / deg + msg_b*(deg>0)
// R6 postmortem: persistent kernel + device-scope fences = L2 flush across 8
// XCDs per barrier (WRITE 19->161 MB, 3.3x regression). Reverted.
// R7: single-pass bucket CSR build (deletes count_k + alloc_k, halves
// atomics), 2-node/wave pairs aggregate, fused finalize in 64-thr blocks
// (1 wave/block -> no VGPR cap -> 160 weights resident, no remat).

constexpr int N_NODES  = 50000;
constexpr int N_EDGES  = 800000;
constexpr int IN_DIM   = 64;
constexpr int EDGE_DIM = 32;
constexpr int OUT_DIM  = 64;
constexpr int CAP      = 48;      // bucket capacity; Poisson(16) max deg ~40
constexpr int OVF_CAP  = 65536;   // overflow list capacity (deg>CAP tails)

// ---------------------------------------------------------------------------
// K1: single-pass bucket build. pos = atomicAdd(cnt[dst]); write (e,src).
// Rare pos>=CAP goes to the overflow list.
// ---------------------------------------------------------------------------
__device__ __forceinline__ void place_one(int dst, int e, int src,
                                          int* cnt, int2* buckets,
                                          int4* ovf, int* ovf_cur) {
    const int pos = atomicAdd(&cnt[dst], 1);
    if (pos < CAP) {
        buckets[(size_t)dst * CAP + pos] = make_int2(e, src);
    } else {
        const int o = atomicAdd(ovf_cur, 1);
        if (o < OVF_CAP) ovf[o] = make_int4(dst, e, src, 0);
    }
}

__global__ __launch_bounds__(256) void place_bucket_k(
    const int* __restrict__ ei, int* cnt, int2* __restrict__ buckets,
    int4* __restrict__ ovf, int* ovf_cur)
{
    const int t = blockIdx.x * 256 + threadIdx.x;
    if (t * 4 + 3 < N_EDGES) {
        const int4 d4 = ((const int4*)(ei + N_EDGES))[t];
        const int4 s4 = ((const int4*)ei)[t];
        place_one(d4.x, 4 * t + 0, s4.x, cnt, buckets, ovf, ovf_cur);
        place_one(d4.y, 4 * t + 1, s4.y, cnt, buckets, ovf, ovf_cur);
        place_one(d4.z, 4 * t + 2, s4.z, cnt, buckets, ovf, ovf_cur);
        place_one(d4.w, 4 * t + 3, s4.w, cnt, buckets, ovf, ovf_cur);
    } else {
        for (int e = t * 4; e < min(t * 4 + 4, N_EDGES); ++e)
            place_one(ei[N_EDGES + e], e, ei[e], cnt, buckets, ovf, ovf_cur);
    }
}

// ---------------------------------------------------------------------------
// K2: gather-reduce, 2 nodes/wave. Bucket rows are contiguous int2 at
// n*CAP. x rows: float4 x 16 lanes (4 edges/instr); ea: float4 x 8 lanes
// (8 edges/instr); shfl_xor reduce; float4 stores zero-fill deg==0 rows.
// Nodes with cnt>CAP scan the (tiny) overflow list before the reduce.
// ---------------------------------------------------------------------------
__global__ __launch_bounds__(256) void aggregate_bucket_k(
    const float* __restrict__ x, const float* __restrict__ ea,
    const int2* __restrict__ buckets, const int* __restrict__ cnt,
    const int4* __restrict__ ovf, const int* __restrict__ ovf_cur,
    float* __restrict__ sum_x, float* __restrict__ sum_ea)
{
    const int lane   = threadIdx.x & 63;
    const int wave   = (blockIdx.x * blockDim.x + threadIdx.x) >> 6;
    const int nwaves = (gridDim.x * blockDim.x) >> 6;

    const int grpx = lane >> 4, colx = lane & 15;  // x: 4 edges/step
    const int grpe = lane >> 3, cole = lane & 7;   // ea: 8 edges/step

    for (int n0 = wave * 2; n0 < N_NODES; n0 += nwaves * 2) {
        const int  nA   = __builtin_amdgcn_readfirstlane(n0);
        const bool hasB = (n0 + 1 < N_NODES);
        const int  nB   = nA + 1;

        const int cFA = __builtin_amdgcn_readfirstlane(cnt[nA]);
        const int cFB = hasB ? __builtin_amdgcn_readfirstlane(cnt[nB]) : 0;
        const int cA  = min(cFA, CAP);
        const int cB  = min(cFB, CAP);

        // index batches (<=48 entries, one int2 gather each, parallel chains)
        int eA = 0, srcA = 0, eB = 0, srcB = 0;
        if (lane < cA) { const int2 p = buckets[(size_t)nA * CAP + lane]; eA = p.x; srcA = p.y; }
        if (lane < cB) { const int2 p = buckets[(size_t)nB * CAP + lane]; eB = p.x; srcB = p.y; }

        float4 axA = {0,0,0,0}, aeA = {0,0,0,0};
        float4 axB = {0,0,0,0}, aeB = {0,0,0,0};

        const int mMax = max(cA, cB);
        for (int j = 0; j < mMax; j += 4) {
            const int jj  = j + grpx;
            const int sjA = __shfl(srcA, jj);
            const int sjB = __shfl(srcB, jj);
            if (jj < cA) {
                const float4 v = ((const float4*)(x + (size_t)sjA * IN_DIM))[colx];
                axA.x += v.x; axA.y += v.y; axA.z += v.z; axA.w += v.w;
            }
            if (jj < cB) {
                const float4 v = ((const float4*)(x + (size_t)sjB * IN_DIM))[colx];
                axB.x += v.x; axB.y += v.y; axB.z += v.z; axB.w += v.w;
            }
        }
        for (int j = 0; j < mMax; j += 8) {
            const int jj  = j + grpe;
            const int ejA = __shfl(eA, jj);
            const int ejB = __shfl(eB, jj);
            if (jj < cA) {
                const float4 v = ((const float4*)(ea + (size_t)ejA * EDGE_DIM))[cole];
                aeA.x += v.x; aeA.y += v.y; aeA.z += v.z; aeA.w += v.w;
            }
            if (jj < cB) {
                const float4 v = ((const float4*)(ea + (size_t)ejB * EDGE_DIM))[cole];
                aeB.x += v.x; aeB.y += v.y; aeB.z += v.z; aeB.w += v.w;
            }
        }

        // rare: overflow entries (deg > CAP). Group 0 accumulates pre-reduce.
        if (cFA > CAP || cFB > CAP) {
            const int novf = min(__builtin_amdgcn_readfirstlane(*ovf_cur), OVF_CAP);
            for (int i = 0; i < novf; ++i) {
                const int4 v = ovf[i];
                const bool mA = (v.x == nA), mB = hasB && (v.x == nB);
                if (mA || mB) {
                    if (grpx == 0) {
                        const float4 t = ((const float4*)(x + (size_t)v.z * IN_DIM))[colx];
                        if (mA) { axA.x += t.x; axA.y += t.y; axA.z += t.z; axA.w += t.w; }
                        else    { axB.x += t.x; axB.y += t.y; axB.z += t.z; axB.w += t.w; }
                    }
                    if (grpe == 0) {
                        const float4 t = ((const float4*)(ea + (size_t)v.y * EDGE_DIM))[cole];
                        if (mA) { aeA.x += t.x; aeA.y += t.y; aeA.z += t.z; aeA.w += t.w; }
                        else    { aeB.x += t.x; aeB.y += t.y; aeB.z += t.z; aeB.w += t.w; }
                    }
                }
            }
        }

#pragma unroll
        for (int mask = 16; mask < 64; mask <<= 1) {
            axA.x += __shfl_xor(axA.x, mask); axA.y += __shfl_xor(axA.y, mask);
            axA.z += __shfl_xor(axA.z, mask); axA.w += __shfl_xor(axA.w, mask);
            axB.x += __shfl_xor(axB.x, mask); axB.y += __shfl_xor(axB.y, mask);
            axB.z += __shfl_xor(axB.z, mask); axB.w += __shfl_xor(axB.w, mask);
        }
#pragma unroll
        for (int mask = 8; mask < 64; mask <<= 1) {
            aeA.x += __shfl_xor(aeA.x, mask); aeA.y += __shfl_xor(aeA.y, mask);
            aeA.z += __shfl_xor(aeA.z, mask); aeA.w += __shfl_xor(aeA.w, mask);
            aeB.x += __shfl_xor(aeB.x, mask); aeB.y += __shfl_xor(aeB.y, mask);
            aeB.z += __shfl_xor(aeB.z, mask); aeB.w += __shfl_xor(aeB.w, mask);
        }

        if (lane < 16) ((float4*)(sum_x + (size_t)nA * IN_DIM))[lane] = axA;
        if (lane < 8)  ((float4*)(sum_ea + (size_t)nA * EDGE_DIM))[lane] = aeA;
        if (hasB) {
            if (lane < 16) ((float4*)(sum_x + (size_t)nB * IN_DIM))[lane] = axB;
            if (lane < 8)  ((float4*)(sum_ea + (size_t)nB * EDGE_DIM))[lane] = aeB;
        }
    }
}

// ---------------------------------------------------------------------------
// K3: fused finalize. 64-thread blocks = 1 wave/block -> VGPR budget up to
// ~256+, so all 96+64 weight floats stay resident (256-thr version remat'd
// at VGPR=124, R4). Lane c owns output column c.
// sum_x_in aliases out; each row touched by exactly one wave.
// ---------------------------------------------------------------------------
__global__ __launch_bounds__(64) void finalize64_k(
    const float* __restrict__ x, const float* sum_x_in,
    const float* __restrict__ sum_ea, const int* __restrict__ cnt,
    const float* __restrict__ msg_w, const float* __restrict__ msg_b,
    const float* __restrict__ self_w, const float* __restrict__ self_b,
    float* out)
{
    const int c = threadIdx.x;  // 0..63

    float wm[96];   // msg_w column c
    float wsf[64];  // self_w column c
#pragma unroll
    for (int k = 0; k < 96; ++k) wm[k] = msg_w[k * OUT_DIM + c];
#pragma unroll
    for (int k = 0; k < 64; ++k) wsf[k] = self_w[k * OUT_DIM + c];
    const float mb = msg_b[c];
    const float sb = self_b[c];

    for (int n0 = blockIdx.x; n0 < N_NODES; n0 += gridDim.x) {
        const int n = __builtin_amdgcn_readfirstlane(n0);

        const float4* r1 = (const float4*)(sum_x_in + (size_t)n * IN_DIM);
        const float4* r2 = (const float4*)(sum_ea   + (size_t)n * EDGE_DIM);
        const float4* r3 = (const float4*)(x        + (size_t)n * IN_DIM);
        const int d = cnt[n];

        float am0 = 0.f, am1 = 0.f, am2 = 0.f, am3 = 0.f;
        float as0 = 0.f, as1 = 0.f, as2 = 0.f, as3 = 0.f;
#pragma unroll
        for (int q = 0; q < 16; ++q) {
            const float4 v = r1[q];
            am0 = fmaf(v.x, wm[4 * q + 0], am0);
            am1 = fmaf(v.y, wm[4 * q + 1], am1);
            am2 = fmaf(v.z, wm[4 * q + 2], am2);
            am3 = fmaf(v.w, wm[4 * q + 3], am3);
        }
#pragma unroll
        for (int q = 0; q < 8; ++q) {
            const float4 v = r2[q];
            am0 = fmaf(v.x, wm[64 + 4 * q + 0], am0);
            am1 = fmaf(v.y, wm[64 + 4 * q + 1], am1);
            am2 = fmaf(v.z, wm[64 + 4 * q + 2], am2);
            am3 = fmaf(v.w, wm[64 + 4 * q + 3], am3);
        }
#pragma unroll
        for (int q = 0; q < 16; ++q) {
            const float4 v = r3[q];
            as0 = fmaf(v.x, wsf[4 * q + 0], as0);
            as1 = fmaf(v.y, wsf[4 * q + 1], as1);
            as2 = fmaf(v.z, wsf[4 * q + 2], as2);
            as3 = fmaf(v.w, wsf[4 * q + 3], as3);
        }

        const float inv  = 1.0f / (float)max(d, 1);
        const float bsel = (d > 0) ? 1.0f : 0.0f;
        const float am   = (am0 + am1) + (am2 + am3);
        const float as   = (as0 + as1) + (as2 + as3);

        out[(size_t)n * OUT_DIM + c] = as + sb + am * inv + mb * bsel;
    }
}

// ---------------------------------------------------------------------------
// Tier-3 fallback: atomic scatter (needs only ~6.6 MB ws).
// ---------------------------------------------------------------------------
__global__ __launch_bounds__(768) void scatter_fb_k(
    const float* __restrict__ x, const int* __restrict__ ei,
    const float* __restrict__ ea, float* sum_x, float* sum_ea, int* deg)
{
    const int t  = threadIdx.x;
    const int el = t / 96;
    const int k  = t - el * 96;
    const int e  = blockIdx.x * 8 + el;
    if (e >= N_EDGES) return;
    const int dst = ei[N_EDGES + e];
    if (k < IN_DIM) {
        const int src = ei[e];
        atomicAdd(&sum_x[dst * IN_DIM + k], x[src * IN_DIM + k]);
        if (k == 0) atomicAdd(&deg[dst], 1);
    } else {
        const int kk = k - IN_DIM;
        atomicAdd(&sum_ea[dst * EDGE_DIM + kk], ea[e * EDGE_DIM + kk]);
    }
}

// ---------------------------------------------------------------------------
extern "C" void kernel_launch(void* const* d_in, const int* in_sizes, int n_in,
                              void* d_out, int out_size, void* d_ws, size_t ws_size,
                              hipStream_t stream) {
    const float* x      = (const float*)d_in[0];
    const int*   ei     = (const int*)d_in[1];   // [2][E]
    const float* ea     = (const float*)d_in[2];
    const float* msg_w  = (const float*)d_in[3];
    const float* msg_b  = (const float*)d_in[4];
    const float* self_w = (const float*)d_in[5];
    const float* self_b = (const float*)d_in[6];

    float* out = (float*)d_out;  // doubles as sum_x accumulator

    // ws layout (ints unless noted):
    //   cnt[50000] | ovf_cur[1] | pad to 16 | buckets[50000*CAP int2]
    //   | ovf[OVF_CAP int4] | sum_ea[1.6M float]
    int*   cnt     = (int*)d_ws;
    int*   ovf_cur = cnt + N_NODES;
    int2*  buckets = (int2*)(cnt + N_NODES + 16);
    int4*  ovf     = (int4*)(buckets + (size_t)N_NODES * CAP);
    float* sum_ea  = (float*)(ovf + OVF_CAP);
    const size_t need_bucket =
        ((size_t)N_NODES + 16 + 2 * (size_t)N_NODES * CAP + 4 * (size_t)OVF_CAP +
         (size_t)N_NODES * EDGE_DIM) * sizeof(int);

    if (ws_size >= need_bucket) {
        hipMemsetAsync(cnt, 0, (N_NODES + 16) * sizeof(int), stream);
        place_bucket_k<<<(N_EDGES / 4 + 255) / 256, 256, 0, stream>>>(
            ei, cnt, buckets, ovf, ovf_cur);
        aggregate_bucket_k<<<(N_NODES / 2 + 3) / 4, 256, 0, stream>>>(
            x, ea, buckets, cnt, ovf, ovf_cur, out, sum_ea);
        finalize64_k<<<4096, 64, 0, stream>>>(
            x, out, sum_ea, cnt, msg_w, msg_b, self_w, self_b, out);
    } else {
        // Fallback: fp32 atomic scatter (R1 path) + fused finalize
        float* fb_sum_ea = (float*)d_ws;
        int*   deg       = (int*)(fb_sum_ea + (size_t)N_NODES * EDGE_DIM);
        hipMemsetAsync(d_out, 0, (size_t)N_NODES * OUT_DIM * sizeof(float), stream);
        hipMemsetAsync(d_ws, 0, (size_t)N_NODES * (EDGE_DIM + 1) * sizeof(float), stream);
        scatter_fb_k<<<(N_EDGES + 7) / 8, 768, 0, stream>>>(
            x, ei, ea, out, fb_sum_ea, deg);
        finalize64_k<<<4096, 64, 0, stream>>>(
            x, out, fb_sum_ea, deg, msg_w, msg_b, self_w, self_b, out);
    }
}